// Round 1
// baseline (242.260 us; speedup 1.0000x reference)
//
#include <hip/hip_runtime.h>

// DWT db4 depthwise stride-2 decomposition.
// x: [B=32, T=16384, C=64] f32 -> out: [B, T2=8190, 2C=128] f32
// out[b,t,c]    = sum_k lo[k] * x[b, reflect(2t+k-1), c]      (c < 64)
// out[b,t,64+c] = sum_k hi[k] * x[b, reflect(2t+k-1), c]
// reflect: m<0 -> -m ; m>T-1 -> 2(T-1)-m   (only touches t=0 and t=T2-1)

#define BT   32
#define TT   16384
#define CC   64
#define T2   8190       // T/2 - 2
#define OC   128        // 2*CC
#define TPT  8          // t-positions per thread (register sliding window)

__global__ __launch_bounds__(256) void dwt_db4_kernel(
    const float* __restrict__ x,
    const float* __restrict__ dec_lo,
    const float* __restrict__ dec_hi,
    float* __restrict__ out)
{
    const int cg   = threadIdx.x;            // 0..15  -> 4 channels via float4
    const int tw   = threadIdx.y;            // 0..15  -> t-strip within tile
    const int tile = blockIdx.x;             // t tile
    const int b    = blockIdx.y;             // batch

    const int c4 = cg * 4;
    const int t0 = (tile * 16 + tw) * TPT;

    // Filters: uniform addresses -> scalar loads, broadcast. 8 taps each.
    float flo[8], fhi[8];
    #pragma unroll
    for (int k = 0; k < 8; ++k) { flo[k] = dec_lo[k]; fhi[k] = dec_hi[k]; }

    const float* __restrict__ xb = x   + (size_t)b * TT * CC;
    float*       __restrict__ ob = out + (size_t)b * T2 * OC;

    const int m0 = 2 * t0 - 1;               // first input row of the strip

    // Sliding window of 8 rows (float4 = 4 channels each)
    float4 w[8];
    #pragma unroll
    for (int i = 0; i < 6; ++i) {
        int m  = m0 + i;
        int mm = m < 0 ? -m : m;                        // left reflect (t0==0 only)
        mm     = mm > (TT - 1) ? 2 * (TT - 1) - mm : mm; // right reflect
        w[i] = *reinterpret_cast<const float4*>(xb + (size_t)mm * CC + c4);
    }

    #pragma unroll
    for (int j = 0; j < TPT; ++j) {
        // two new rows per output; m >= 5 here so no left reflect needed
        {
            int m  = m0 + 2 * j + 6;
            int mm = m > (TT - 1) ? 2 * (TT - 1) - m : m;
            w[6] = *reinterpret_cast<const float4*>(xb + (size_t)mm * CC + c4);
            m  = m0 + 2 * j + 7;
            mm = m > (TT - 1) ? 2 * (TT - 1) - m : m;
            w[7] = *reinterpret_cast<const float4*>(xb + (size_t)mm * CC + c4);
        }

        const int t = t0 + j;
        if (t < T2) {
            float4 alo, ahi;
            alo.x = alo.y = alo.z = alo.w = 0.0f;
            ahi.x = ahi.y = ahi.z = ahi.w = 0.0f;
            #pragma unroll
            for (int k = 0; k < 8; ++k) {
                alo.x = fmaf(flo[k], w[k].x, alo.x);
                alo.y = fmaf(flo[k], w[k].y, alo.y);
                alo.z = fmaf(flo[k], w[k].z, alo.z);
                alo.w = fmaf(flo[k], w[k].w, alo.w);
                ahi.x = fmaf(fhi[k], w[k].x, ahi.x);
                ahi.y = fmaf(fhi[k], w[k].y, ahi.y);
                ahi.z = fmaf(fhi[k], w[k].z, ahi.z);
                ahi.w = fmaf(fhi[k], w[k].w, ahi.w);
            }
            *reinterpret_cast<float4*>(ob + (size_t)t * OC + c4)      = alo;
            *reinterpret_cast<float4*>(ob + (size_t)t * OC + CC + c4) = ahi;
        }

        // shift window by 2 (stride-2)
        #pragma unroll
        for (int i = 0; i < 6; ++i) w[i] = w[i + 2];
    }
}

extern "C" void kernel_launch(void* const* d_in, const int* in_sizes, int n_in,
                              void* d_out, int out_size, void* d_ws, size_t ws_size,
                              hipStream_t stream)
{
    const float* x      = (const float*)d_in[0];
    const float* dec_lo = (const float*)d_in[1];
    const float* dec_hi = (const float*)d_in[2];
    float*       out    = (float*)d_out;

    dim3 block(16, 16);
    // 16 strips * TPT outputs = 128 t per tile; ceil(8190/128) = 64 tiles
    dim3 grid((T2 + 16 * TPT - 1) / (16 * TPT), BT);

    hipLaunchKernelGGL(dwt_db4_kernel, grid, block, 0, stream,
                       x, dec_lo, dec_hi, out);
}

// Round 2
// 226.282 us; speedup vs baseline: 1.0706x; 1.0706x over previous
//
#include <hip/hip_runtime.h>

// DWT db4 depthwise stride-2 decomposition.
// x: [B=32, T=16384, C=64] f32 -> out: [B, T2=8190, 2C=128] f32
// out[b,t,c]    = sum_k lo[k] * x[b, reflect(2t+k-1), c]      (c < 64)
// out[b,t,64+c] = sum_k hi[k] * x[b, reflect(2t+k-1), c]
// reflect: m<0 -> -m ; m>T-1 -> 2(T-1)-m
//
// R2 structure: one thread = (4 channels via float4) x (pair of outputs t,t+1).
// The pair needs input rows 2t-1 .. 2t+8 (10 rows) -- all 10 float4 loads are
// independent and issued before any use => ~10 outstanding loads/thread for
// latency hiding (R1 had ~2; VGPR=24 showed the compiler serialized the
// sliding window). Logical re-read (2.5x) is absorbed by L1/L2.

#define BT   32
#define TT   16384
#define CC   64
#define T2   8190       // T/2 - 2
#define OC   128        // 2*CC
#define NPAIR (T2 / 2)  // 4095

__global__ __launch_bounds__(256) void dwt_db4_pair_kernel(
    const float* __restrict__ x,
    const float* __restrict__ dec_lo,
    const float* __restrict__ dec_hi,
    float* __restrict__ out)
{
    const int tid  = threadIdx.x;
    const int cg   = tid & 15;               // channel group: 4 ch via float4
    const int tp   = tid >> 4;               // 0..15: pair slot within block
    const int pair = blockIdx.x * 16 + tp;
    const int b    = blockIdx.y;
    if (pair >= NPAIR) return;

    const int t  = pair * 2;
    const int c4 = cg * 4;

    // Filters: uniform addresses -> scalar broadcast loads.
    float flo[8], fhi[8];
    #pragma unroll
    for (int k = 0; k < 8; ++k) { flo[k] = dec_lo[k]; fhi[k] = dec_hi[k]; }

    const float* __restrict__ xb = x + (size_t)b * TT * CC;

    // 10-row window, all loads independent.
    const int m0 = 2 * t - 1;
    float4 w[10];
    #pragma unroll
    for (int i = 0; i < 10; ++i) {
        int m  = m0 + i;
        int mm = m < 0 ? -m : m;                          // left reflect (t==0)
        mm     = mm > (TT - 1) ? 2 * (TT - 1) - mm : mm;  // right reflect (tail)
        w[i] = *reinterpret_cast<const float4*>(xb + (size_t)mm * CC + c4);
    }

    float4 alo0, ahi0, alo1, ahi1;
    alo0.x = alo0.y = alo0.z = alo0.w = 0.0f;
    ahi0.x = ahi0.y = ahi0.z = ahi0.w = 0.0f;
    alo1.x = alo1.y = alo1.z = alo1.w = 0.0f;
    ahi1.x = ahi1.y = ahi1.z = ahi1.w = 0.0f;

    #pragma unroll
    for (int k = 0; k < 8; ++k) {
        // output t uses rows w[0..7], output t+1 uses rows w[2..9]
        alo0.x = fmaf(flo[k], w[k].x, alo0.x);
        alo0.y = fmaf(flo[k], w[k].y, alo0.y);
        alo0.z = fmaf(flo[k], w[k].z, alo0.z);
        alo0.w = fmaf(flo[k], w[k].w, alo0.w);
        ahi0.x = fmaf(fhi[k], w[k].x, ahi0.x);
        ahi0.y = fmaf(fhi[k], w[k].y, ahi0.y);
        ahi0.z = fmaf(fhi[k], w[k].z, ahi0.z);
        ahi0.w = fmaf(fhi[k], w[k].w, ahi0.w);

        alo1.x = fmaf(flo[k], w[k + 2].x, alo1.x);
        alo1.y = fmaf(flo[k], w[k + 2].y, alo1.y);
        alo1.z = fmaf(flo[k], w[k + 2].z, alo1.z);
        alo1.w = fmaf(flo[k], w[k + 2].w, alo1.w);
        ahi1.x = fmaf(fhi[k], w[k + 2].x, ahi1.x);
        ahi1.y = fmaf(fhi[k], w[k + 2].y, ahi1.y);
        ahi1.z = fmaf(fhi[k], w[k + 2].z, ahi1.z);
        ahi1.w = fmaf(fhi[k], w[k + 2].w, ahi1.w);
    }

    float* __restrict__ ob = out + (size_t)b * T2 * OC + (size_t)t * OC;
    *reinterpret_cast<float4*>(ob + c4)           = alo0;
    *reinterpret_cast<float4*>(ob + CC + c4)      = ahi0;
    *reinterpret_cast<float4*>(ob + OC + c4)      = alo1;
    *reinterpret_cast<float4*>(ob + OC + CC + c4) = ahi1;
}

extern "C" void kernel_launch(void* const* d_in, const int* in_sizes, int n_in,
                              void* d_out, int out_size, void* d_ws, size_t ws_size,
                              hipStream_t stream)
{
    const float* x      = (const float*)d_in[0];
    const float* dec_lo = (const float*)d_in[1];
    const float* dec_hi = (const float*)d_in[2];
    float*       out    = (float*)d_out;

    dim3 block(256);
    // 16 pairs per block -> ceil(4095/16) = 256 tiles; x 32 batches
    dim3 grid((NPAIR + 15) / 16, BT);

    hipLaunchKernelGGL(dwt_db4_pair_kernel, grid, block, 0, stream,
                       x, dec_lo, dec_hi, out);
}